// Round 1
// baseline (2901.254 us; speedup 1.0000x reference)
//
#include <hip/hip_runtime.h>

// BusStopGNN: 2-layer GCN + linear head on MI355X.
// Round 1: correctness-first baseline. Aggregation via atomicAdd scatter
// (predicted bottleneck); self-loop fused into activation kernel.

#define GNN_N 100000
#define GNN_E 1600000

// deg counting: one atomicAdd per edge at dst (self-loop handled as +1.0 in k_rsqrt)
__global__ void k_deg(const int* __restrict__ dst, float* __restrict__ deg, int E) {
    int e = blockIdx.x * blockDim.x + threadIdx.x;
    if (e < E) atomicAdd(&deg[dst[e]], 1.0f);
}

// dis[i] = rsqrt(deg[i] + 1)   (in-place on the deg buffer; +1 = self-loop)
__global__ void k_rsqrt(float* __restrict__ dis, int n) {
    int i = blockIdx.x * blockDim.x + threadIdx.x;
    if (i < n) dis[i] = rsqrtf(dis[i] + 1.0f);
}

// Y[n x 64] = X[n x 64] @ W[64 x 64]; one thread per row, W staged in LDS.
// All lanes read the same W element per FMA -> LDS broadcast, conflict-free.
__global__ __launch_bounds__(256) void k_mm64(const float* __restrict__ X,
                                              const float* __restrict__ W,
                                              float* __restrict__ Y, int n) {
    __shared__ float4 Ws[64 * 16];  // W[k][j4] as float4
    int tid = threadIdx.x;
    for (int i = tid; i < 64 * 16; i += 256)
        Ws[i] = ((const float4*)W)[i];
    __syncthreads();
    int row = blockIdx.x * 256 + tid;
    if (row >= n) return;
    float4 xr[16];
    const float4* xp = (const float4*)(X + (size_t)row * 64);
#pragma unroll
    for (int i = 0; i < 16; ++i) xr[i] = xp[i];
    float acc[64];
#pragma unroll
    for (int j = 0; j < 64; ++j) acc[j] = 0.0f;
#pragma unroll
    for (int k = 0; k < 64; ++k) {
        // k is compile-time constant (full unroll) -> xr indexing stays in registers
        float xv = ((const float*)xr)[k];
#pragma unroll
        for (int j4 = 0; j4 < 16; ++j4) {
            float4 w = Ws[k * 16 + j4];
            acc[j4 * 4 + 0] += xv * w.x;
            acc[j4 * 4 + 1] += xv * w.y;
            acc[j4 * 4 + 2] += xv * w.z;
            acc[j4 * 4 + 3] += xv * w.w;
        }
    }
    float4* yp = (float4*)(Y + (size_t)row * 64);
#pragma unroll
    for (int j4 = 0; j4 < 16; ++j4)
        yp[j4] = make_float4(acc[j4 * 4 + 0], acc[j4 * 4 + 1], acc[j4 * 4 + 2], acc[j4 * 4 + 3]);
}

// Edge scatter: 16 threads per edge, each handles one float4 channel chunk.
// agg[dst] += H[src] * (dis[src]*dis[dst])
__global__ void k_scatter(const float* __restrict__ H, const int* __restrict__ src,
                          const int* __restrict__ dst, const float* __restrict__ dis,
                          float* __restrict__ agg, int E) {
    int t = blockIdx.x * blockDim.x + threadIdx.x;
    int e = t >> 4;
    int c4 = t & 15;
    if (e >= E) return;
    int s = src[e], d = dst[e];
    float norm = dis[s] * dis[d];
    float4 v = ((const float4*)(H + (size_t)s * 64))[c4];
    float* o = agg + (size_t)d * 64 + c4 * 4;
    atomicAdd(o + 0, v.x * norm);
    atomicAdd(o + 1, v.y * norm);
    atomicAdd(o + 2, v.z * norm);
    atomicAdd(o + 3, v.w * norm);
}

// out = relu(agg + Hlin*dis^2 + b)   (self-loop term fused; elementwise, aliasing-safe)
__global__ void k_act(const float* __restrict__ Hlin, const float* __restrict__ agg,
                      const float* __restrict__ dis, const float* __restrict__ b,
                      float* __restrict__ outp, int n) {
    int t = blockIdx.x * blockDim.x + threadIdx.x;
    int i = t >> 4;
    int c4 = t & 15;
    if (i >= n) return;
    float dv = dis[i];
    float d2 = dv * dv;
    float4 hl = ((const float4*)(Hlin + (size_t)i * 64))[c4];
    float4 ag = ((const float4*)(agg + (size_t)i * 64))[c4];
    float4 bb = ((const float4*)b)[c4];
    float4 r;
    r.x = fmaxf(ag.x + hl.x * d2 + bb.x, 0.0f);
    r.y = fmaxf(ag.y + hl.y * d2 + bb.y, 0.0f);
    r.z = fmaxf(ag.z + hl.z * d2 + bb.z, 0.0f);
    r.w = fmaxf(ag.w + hl.w * d2 + bb.w, 0.0f);
    ((float4*)(outp + (size_t)i * 64))[c4] = r;
}

// out[i] = dot(H[i], Wp) + bp
__global__ void k_out(const float* __restrict__ H, const float* __restrict__ Wp,
                      const float* __restrict__ bp, float* __restrict__ out, int n) {
    __shared__ float Ws[64];
    if (threadIdx.x < 64) Ws[threadIdx.x] = Wp[threadIdx.x];
    __syncthreads();
    int i = blockIdx.x * blockDim.x + threadIdx.x;
    if (i >= n) return;
    const float4* hp = (const float4*)(H + (size_t)i * 64);
    float s = 0.0f;
#pragma unroll
    for (int j4 = 0; j4 < 16; ++j4) {
        float4 h = hp[j4];
        s += h.x * Ws[j4 * 4 + 0] + h.y * Ws[j4 * 4 + 1] + h.z * Ws[j4 * 4 + 2] + h.w * Ws[j4 * 4 + 3];
    }
    out[i] = s + bp[0];
}

extern "C" void kernel_launch(void* const* d_in, const int* in_sizes, int n_in,
                              void* d_out, int out_size, void* d_ws, size_t ws_size,
                              hipStream_t stream) {
    const float* x  = (const float*)d_in[0];
    const int*   ei = (const int*)d_in[1];   // [2, E] flat, int32 per harness convention
    const float* W1 = (const float*)d_in[2];
    const float* b1 = (const float*)d_in[3];
    const float* W2 = (const float*)d_in[4];
    const float* b2 = (const float*)d_in[5];
    const float* Wp = (const float*)d_in[6];
    const float* bp = (const float*)d_in[7];
    float* out = (float*)d_out;

    const int N = GNN_N, E = GNN_E;
    const int* srcv = ei;
    const int* dstv = ei + E;

    char* ws = (char*)d_ws;
    float* dis  = (float*)ws;                               // N floats (deg -> dis in place)
    float* bufA = (float*)(ws + 400384);                    // N*64 floats
    float* bufB = (float*)(ws + 400384 + (size_t)N * 64 * 4);  // N*64 floats

    // degree + normalization
    hipMemsetAsync(dis, 0, (size_t)N * sizeof(float), stream);
    k_deg<<<(E + 255) / 256, 256, 0, stream>>>(dstv, dis, E);
    k_rsqrt<<<(N + 255) / 256, 256, 0, stream>>>(dis, N);

    // layer 1
    k_mm64<<<(N + 255) / 256, 256, 0, stream>>>(x, W1, bufA, N);           // bufA = x@W1
    hipMemsetAsync(bufB, 0, (size_t)N * 64 * 4, stream);
    k_scatter<<<(E * 16 + 255) / 256, 256, 0, stream>>>(bufA, srcv, dstv, dis, bufB, E);
    k_act<<<(N * 16 + 255) / 256, 256, 0, stream>>>(bufA, bufB, dis, b1, bufA, N);  // bufA = h1

    // layer 2
    k_mm64<<<(N + 255) / 256, 256, 0, stream>>>(bufA, W2, bufB, N);        // bufB = h1@W2
    hipMemsetAsync(bufA, 0, (size_t)N * 64 * 4, stream);
    k_scatter<<<(E * 16 + 255) / 256, 256, 0, stream>>>(bufB, srcv, dstv, dis, bufA, E);
    k_act<<<(N * 16 + 255) / 256, 256, 0, stream>>>(bufB, bufA, dis, b2, bufA, N);  // bufA = h2

    // head
    k_out<<<(N + 255) / 256, 256, 0, stream>>>(bufA, Wp, bp, out, N);
}

// Round 2
// 423.740 us; speedup vs baseline: 6.8468x; 6.8468x over previous
//
#include <hip/hip_runtime.h>

// BusStopGNN round 2: replace float-atomic scatter with device-built CSR
// (by dst) + pull-mode wave-per-node gather. Self-loop + bias + ReLU fused
// into the gather kernel. No float atomics anywhere.

#define GNN_N 100000
#define GNN_E 1600000

// ---- CSR build ----

// int degree count per dst
__global__ void k_degi(const int* __restrict__ dst, int* __restrict__ deg, int E) {
    int e = blockIdx.x * blockDim.x + threadIdx.x;
    if (e < E) atomicAdd(&deg[dst[e]], 1);
}

// per-wave bump allocation: rowptr[i] = global offset for node i's edge list.
// Also computes dis[i] = rsqrt(deg[i]+1) (self-loop included in degree).
__global__ void k_scan(const int* __restrict__ deg, int* __restrict__ rowptr,
                       int* __restrict__ fill, float* __restrict__ dis,
                       int* __restrict__ ctr, int n) {
    int i = blockIdx.x * blockDim.x + threadIdx.x;
    int lane = threadIdx.x & 63;
    int d = (i < n) ? deg[i] : 0;
    // inclusive wave scan
    int v = d;
#pragma unroll
    for (int o = 1; o < 64; o <<= 1) {
        int t = __shfl_up(v, o);
        if (lane >= o) v += t;
    }
    int total = __shfl(v, 63);
    int base = 0;
    if (lane == 63) base = atomicAdd(ctr, total);
    base = __shfl(base, 63);
    if (i < n) {
        int off = base + v - d;  // exclusive
        rowptr[i] = off;
        fill[i] = off;
        dis[i] = rsqrtf((float)d + 1.0f);
    }
}

// scatter edge source ids into CSR slots
__global__ void k_fill(const int* __restrict__ src, const int* __restrict__ dst,
                       int* __restrict__ fill, int* __restrict__ csr, int E) {
    int e = blockIdx.x * blockDim.x + threadIdx.x;
    if (e >= E) return;
    int slot = atomicAdd(&fill[dst[e]], 1);
    csr[slot] = src[e];
}

// ---- dense 64x64 matmul: one thread per row, W staged in LDS ----
__global__ __launch_bounds__(256) void k_mm64(const float* __restrict__ X,
                                              const float* __restrict__ W,
                                              float* __restrict__ Y, int n) {
    __shared__ float4 Ws[64 * 16];
    int tid = threadIdx.x;
    for (int i = tid; i < 64 * 16; i += 256)
        Ws[i] = ((const float4*)W)[i];
    __syncthreads();
    int row = blockIdx.x * 256 + tid;
    if (row >= n) return;
    float4 xr[16];
    const float4* xp = (const float4*)(X + (size_t)row * 64);
#pragma unroll
    for (int i = 0; i < 16; ++i) xr[i] = xp[i];
    float acc[64];
#pragma unroll
    for (int j = 0; j < 64; ++j) acc[j] = 0.0f;
#pragma unroll
    for (int k = 0; k < 64; ++k) {
        float xv = ((const float*)xr)[k];
#pragma unroll
        for (int j4 = 0; j4 < 16; ++j4) {
            float4 w = Ws[k * 16 + j4];
            acc[j4 * 4 + 0] += xv * w.x;
            acc[j4 * 4 + 1] += xv * w.y;
            acc[j4 * 4 + 2] += xv * w.z;
            acc[j4 * 4 + 3] += xv * w.w;
        }
    }
    float4* yp = (float4*)(Y + (size_t)row * 64);
#pragma unroll
    for (int j4 = 0; j4 < 16; ++j4)
        yp[j4] = make_float4(acc[j4 * 4 + 0], acc[j4 * 4 + 1], acc[j4 * 4 + 2], acc[j4 * 4 + 3]);
}

// ---- pull-mode aggregation: one wave per node, lane = channel ----
// out[i][lane] = relu( sum_{e in CSR[i]} H[s][lane]*dis[s]*dis[i]
//                      + H[i][lane]*dis[i]^2 + b[lane] )
__global__ __launch_bounds__(256) void k_gather(const float* __restrict__ H,
                                                const int* __restrict__ csr,
                                                const int* __restrict__ rowptr,
                                                const int* __restrict__ deg,
                                                const float* __restrict__ dis,
                                                const float* __restrict__ b,
                                                float* __restrict__ out, int n) {
    int node = blockIdx.x * 4 + (threadIdx.x >> 6);
    int lane = threadIdx.x & 63;
    if (node >= n) return;
    int base = rowptr[node];
    int cnt = deg[node];
    float dd = dis[node];
    float acc = 0.0f;
    int j = 0;
    for (; j + 4 <= cnt; j += 4) {  // 4 independent chains for latency hiding
        int s0 = csr[base + j + 0];
        int s1 = csr[base + j + 1];
        int s2 = csr[base + j + 2];
        int s3 = csr[base + j + 3];
        float w0 = dis[s0], w1 = dis[s1], w2 = dis[s2], w3 = dis[s3];
        float h0 = H[(size_t)s0 * 64 + lane];
        float h1 = H[(size_t)s1 * 64 + lane];
        float h2 = H[(size_t)s2 * 64 + lane];
        float h3 = H[(size_t)s3 * 64 + lane];
        acc += h0 * w0 + h1 * w1 + h2 * w2 + h3 * w3;
    }
    for (; j < cnt; ++j) {
        int s = csr[base + j];
        acc += H[(size_t)s * 64 + lane] * dis[s];
    }
    // self-loop + bias + relu (edge norms all share dis[node] -> factor out)
    float r = acc * dd + H[(size_t)node * 64 + lane] * dd * dd + b[lane];
    out[(size_t)node * 64 + lane] = fmaxf(r, 0.0f);
}

// ---- head: out[i] = dot(H[i], Wp) + bp ----
__global__ void k_out(const float* __restrict__ H, const float* __restrict__ Wp,
                      const float* __restrict__ bp, float* __restrict__ out, int n) {
    __shared__ float Ws[64];
    if (threadIdx.x < 64) Ws[threadIdx.x] = Wp[threadIdx.x];
    __syncthreads();
    int i = blockIdx.x * blockDim.x + threadIdx.x;
    if (i >= n) return;
    const float4* hp = (const float4*)(H + (size_t)i * 64);
    float s = 0.0f;
#pragma unroll
    for (int j4 = 0; j4 < 16; ++j4) {
        float4 h = hp[j4];
        s += h.x * Ws[j4 * 4 + 0] + h.y * Ws[j4 * 4 + 1] + h.z * Ws[j4 * 4 + 2] + h.w * Ws[j4 * 4 + 3];
    }
    out[i] = s + bp[0];
}

extern "C" void kernel_launch(void* const* d_in, const int* in_sizes, int n_in,
                              void* d_out, int out_size, void* d_ws, size_t ws_size,
                              hipStream_t stream) {
    const float* x  = (const float*)d_in[0];
    const int*   ei = (const int*)d_in[1];
    const float* W1 = (const float*)d_in[2];
    const float* b1 = (const float*)d_in[3];
    const float* W2 = (const float*)d_in[4];
    const float* b2 = (const float*)d_in[5];
    const float* Wp = (const float*)d_in[6];
    const float* bp = (const float*)d_in[7];
    float* out = (float*)d_out;

    const int N = GNN_N, E = GNN_E;
    const int* srcv = ei;
    const int* dstv = ei + E;

    // workspace layout (512-aligned chunks)
    char* ws = (char*)d_ws;
    int*   deg    = (int*)(ws + 0);                       // N ints
    int*   ctr    = (int*)(ws + 400384);                  // 1 int
    float* dis    = (float*)(ws + 400384 + 512);          // N floats
    int*   rowptr = (int*)(ws + 801280);                  // N ints
    int*   fill   = (int*)(ws + 1201664);                 // N ints
    int*   csr    = (int*)(ws + 1602048);                 // E ints
    float* bufA   = (float*)(ws + 8002048);               // N*64 floats
    float* bufB   = (float*)(ws + 8002048 + (size_t)N * 64 * 4);

    // CSR build (deg+ctr contiguous -> one memset)
    hipMemsetAsync(deg, 0, 400384 + 512, stream);
    k_degi<<<(E + 255) / 256, 256, 0, stream>>>(dstv, deg, E);
    k_scan<<<(N + 255) / 256, 256, 0, stream>>>(deg, rowptr, fill, dis, ctr, N);
    k_fill<<<(E + 255) / 256, 256, 0, stream>>>(srcv, dstv, fill, csr, E);

    // layer 1
    k_mm64<<<(N + 255) / 256, 256, 0, stream>>>(x, W1, bufA, N);
    k_gather<<<(N + 3) / 4, 256, 0, stream>>>(bufA, csr, rowptr, deg, dis, b1, bufB, N);
    // layer 2
    k_mm64<<<(N + 255) / 256, 256, 0, stream>>>(bufB, W2, bufA, N);
    k_gather<<<(N + 3) / 4, 256, 0, stream>>>(bufA, csr, rowptr, deg, dis, b2, bufB, N);
    // head
    k_out<<<(N + 255) / 256, 256, 0, stream>>>(bufB, Wp, bp, out, N);
}

// Round 3
// 261.201 us; speedup vs baseline: 11.1073x; 1.6223x over previous
//
#include <hip/hip_runtime.h>

// BusStopGNN round 3: CSR build via two-level counting sort (no global
// atomics, no memsets). dis[] folded into matmul epilogue so gather has no
// per-edge dis loads. Gather: wave-per-node pull, fused self-loop+bias+relu.

#define GNN_N 100000
#define GNN_E 1600000
#define NBUCK 391   // ceil(N/256), bucket = dst >> 8
#define NBLK  256   // edge-chunk blocks for hist/partition
#define EPB   6250  // E / NBLK (exact)

// ---- Pass 1: per-block LDS histogram over dst buckets ----
__global__ __launch_bounds__(256) void k_hist(const int* __restrict__ dst,
                                              int* __restrict__ hist) {
    __shared__ int h[NBUCK];
    for (int i = threadIdx.x; i < NBUCK; i += 256) h[i] = 0;
    __syncthreads();
    int b = blockIdx.x;
    int e0 = b * EPB, e1 = min(e0 + EPB, GNN_E);
    for (int e = e0 + threadIdx.x; e < e1; e += 256)
        atomicAdd(&h[dst[e] >> 8], 1);
    __syncthreads();
    for (int i = threadIdx.x; i < NBUCK; i += 256)
        hist[b * NBUCK + i] = h[i];
}

// ---- Pass 2: column scan (prefix over blocks per bucket) + bucket bases ----
__global__ __launch_bounds__(512) void k_colscan(int* __restrict__ hist,
                                                 int* __restrict__ bbase) {
    __shared__ int tot[NBUCK];
    int k = threadIdx.x;
    if (k < NBUCK) {
        int run = 0;
        for (int b = 0; b < NBLK; ++b) {       // lanes k consecutive -> coalesced
            int idx = b * NBUCK + k;
            int t = hist[idx];
            hist[idx] = run;                   // intra-column exclusive prefix
            run += t;
        }
        tot[k] = run;
    }
    __syncthreads();
    if (threadIdx.x == 0) {
        int run = 0;
        for (int i = 0; i < NBUCK; ++i) { int t = tot[i]; tot[i] = run; run += t; }
    }
    __syncthreads();
    if (k < NBUCK) bbase[k] = tot[k];
    if (threadIdx.x == 0) bbase[NBUCK] = GNN_E;
}

// ---- Pass 3: partition edges into bucket-contiguous regions ----
// slot ranges are disjoint per (block,bucket) -> no cross-block line sharing.
// pack: (dst & 255) << 17 | src   (src < 2^17)
__global__ __launch_bounds__(256) void k_part(const int* __restrict__ src,
                                              const int* __restrict__ dst,
                                              const int* __restrict__ hist,
                                              const int* __restrict__ bbase,
                                              unsigned int* __restrict__ part) {
    __shared__ int off[NBUCK];
    int b = blockIdx.x;
    for (int i = threadIdx.x; i < NBUCK; i += 256)
        off[i] = bbase[i] + hist[b * NBUCK + i];
    __syncthreads();
    int e0 = b * EPB, e1 = min(e0 + EPB, GNN_E);
    for (int e = e0 + threadIdx.x; e < e1; e += 256) {
        int d = dst[e], s = src[e];
        int slot = atomicAdd(&off[d >> 8], 1);   // LDS atomic
        part[slot] = ((unsigned int)(d & 255) << 17) | (unsigned int)s;
    }
}

// ---- Pass 4: per-bucket counting sort -> csr, rowptr, deg, dis ----
__global__ __launch_bounds__(256) void k_bsort(const unsigned int* __restrict__ part,
                                               const int* __restrict__ bbase,
                                               int* __restrict__ csr,
                                               int* __restrict__ rowptr,
                                               int* __restrict__ deg,
                                               float* __restrict__ dis) {
    __shared__ int cnt[256];
    __shared__ int pos[256];
    int k = blockIdx.x;
    int t = threadIdx.x;
    cnt[t] = 0;
    __syncthreads();
    int e0 = bbase[k], e1 = bbase[k + 1];
    for (int e = e0 + t; e < e1; e += 256)
        atomicAdd(&cnt[part[e] >> 17], 1);
    __syncthreads();
    if (t == 0) {
        int run = 0;
        for (int i = 0; i < 256; ++i) { int c = cnt[i]; pos[i] = run; run += c; }
    }
    __syncthreads();
    int node = k * 256 + t;
    if (node < GNN_N) {
        rowptr[node] = e0 + pos[t];
        deg[node]    = cnt[t];
        dis[node]    = rsqrtf((float)cnt[t] + 1.0f);
    }
    __syncthreads();
    for (int e = e0 + t; e < e1; e += 256) {
        unsigned int p = part[e];
        int slot = e0 + atomicAdd(&pos[p >> 17], 1);
        csr[slot] = (int)(p & 0x1FFFF);
    }
}

// ---- dense 64x64 matmul + dis-scale epilogue: Y[row] = (X@W)[row]*dis[row] ----
__global__ __launch_bounds__(256) void k_mm64(const float* __restrict__ X,
                                              const float* __restrict__ W,
                                              const float* __restrict__ dis,
                                              float* __restrict__ Y, int n) {
    __shared__ float4 Ws[64 * 16];
    int tid = threadIdx.x;
    for (int i = tid; i < 64 * 16; i += 256)
        Ws[i] = ((const float4*)W)[i];
    __syncthreads();
    int row = blockIdx.x * 256 + tid;
    if (row >= n) return;
    float4 xr[16];
    const float4* xp = (const float4*)(X + (size_t)row * 64);
#pragma unroll
    for (int i = 0; i < 16; ++i) xr[i] = xp[i];
    float acc[64];
#pragma unroll
    for (int j = 0; j < 64; ++j) acc[j] = 0.0f;
#pragma unroll
    for (int k = 0; k < 64; ++k) {
        float xv = ((const float*)xr)[k];
#pragma unroll
        for (int j4 = 0; j4 < 16; ++j4) {
            float4 w = Ws[k * 16 + j4];
            acc[j4 * 4 + 0] += xv * w.x;
            acc[j4 * 4 + 1] += xv * w.y;
            acc[j4 * 4 + 2] += xv * w.z;
            acc[j4 * 4 + 3] += xv * w.w;
        }
    }
    float dv = dis[row];
    float4* yp = (float4*)(Y + (size_t)row * 64);
#pragma unroll
    for (int j4 = 0; j4 < 16; ++j4)
        yp[j4] = make_float4(acc[j4 * 4 + 0] * dv, acc[j4 * 4 + 1] * dv,
                             acc[j4 * 4 + 2] * dv, acc[j4 * 4 + 3] * dv);
}

// ---- pull gather: out[i] = relu( dis[i]*(sum Hs[s] + Hs[i]) + b ) ----
__global__ __launch_bounds__(256) void k_gather(const float* __restrict__ Hs,
                                                const int* __restrict__ csr,
                                                const int* __restrict__ rowptr,
                                                const int* __restrict__ deg,
                                                const float* __restrict__ dis,
                                                const float* __restrict__ b,
                                                float* __restrict__ out, int n) {
    int node = blockIdx.x * 4 + (threadIdx.x >> 6);
    int lane = threadIdx.x & 63;
    if (node >= n) return;
    int base = rowptr[node];
    int cnt = deg[node];
    float dd = dis[node];
    float acc = 0.0f;
    int j = 0;
    for (; j + 4 <= cnt; j += 4) {
        int s0 = csr[base + j + 0];
        int s1 = csr[base + j + 1];
        int s2 = csr[base + j + 2];
        int s3 = csr[base + j + 3];
        acc += Hs[(size_t)s0 * 64 + lane] + Hs[(size_t)s1 * 64 + lane]
             + Hs[(size_t)s2 * 64 + lane] + Hs[(size_t)s3 * 64 + lane];
    }
    for (; j < cnt; ++j)
        acc += Hs[(size_t)csr[base + j] * 64 + lane];
    float r = dd * (acc + Hs[(size_t)node * 64 + lane]) + b[lane];
    out[(size_t)node * 64 + lane] = fmaxf(r, 0.0f);
}

// ---- head: out[i] = dot(H[i], Wp) + bp ----
__global__ void k_out(const float* __restrict__ H, const float* __restrict__ Wp,
                      const float* __restrict__ bp, float* __restrict__ out, int n) {
    __shared__ float Ws[64];
    if (threadIdx.x < 64) Ws[threadIdx.x] = Wp[threadIdx.x];
    __syncthreads();
    int i = blockIdx.x * blockDim.x + threadIdx.x;
    if (i >= n) return;
    const float4* hp = (const float4*)(H + (size_t)i * 64);
    float s = 0.0f;
#pragma unroll
    for (int j4 = 0; j4 < 16; ++j4) {
        float4 h = hp[j4];
        s += h.x * Ws[j4 * 4 + 0] + h.y * Ws[j4 * 4 + 1] + h.z * Ws[j4 * 4 + 2] + h.w * Ws[j4 * 4 + 3];
    }
    out[i] = s + bp[0];
}

extern "C" void kernel_launch(void* const* d_in, const int* in_sizes, int n_in,
                              void* d_out, int out_size, void* d_ws, size_t ws_size,
                              hipStream_t stream) {
    const float* x  = (const float*)d_in[0];
    const int*   ei = (const int*)d_in[1];
    const float* W1 = (const float*)d_in[2];
    const float* b1 = (const float*)d_in[3];
    const float* W2 = (const float*)d_in[4];
    const float* b2 = (const float*)d_in[5];
    const float* Wp = (const float*)d_in[6];
    const float* bp = (const float*)d_in[7];
    float* out = (float*)d_out;

    const int N = GNN_N, E = GNN_E;
    const int* srcv = ei;
    const int* dstv = ei + E;

    // workspace layout (bytes):
    //   hist   @ 0        : NBLK*NBUCK ints = 400,384
    //   bbase  @ 400,896  : 392 ints
    //   rowptr @ 402,944  : N ints
    //   deg    @ 802,944  : N ints
    //   dis    @ 1,202,944: N floats
    //   csr    @ 1,603,584: E ints (6.4 MB)
    //   bufA   @ 8,003,584: N*64 floats (25.6 MB)
    //   bufB   @ 33,603,584: N*64 floats (25.6 MB)
    //   part   @ 33,603,584: E u32 (6.4 MB) -- ALIASES bufB: part is dead
    //            before gather1 writes bufB (same-stream serialization).
    char* ws = (char*)d_ws;
    int*   hist   = (int*)(ws + 0);
    int*   bbase  = (int*)(ws + 400896);
    int*   rowptr = (int*)(ws + 402944);
    int*   deg    = (int*)(ws + 802944);
    float* dis    = (float*)(ws + 1202944);
    int*   csr    = (int*)(ws + 1603584);
    float* bufA   = (float*)(ws + 8003584);
    float* bufB   = (float*)(ws + 33603584);
    unsigned int* part = (unsigned int*)(ws + 33603584);

    // CSR build: two-level counting sort (no global atomics, no memsets)
    k_hist   <<<NBLK, 256, 0, stream>>>(dstv, hist);
    k_colscan<<<1, 512, 0, stream>>>(hist, bbase);
    k_part   <<<NBLK, 256, 0, stream>>>(srcv, dstv, hist, bbase, part);
    k_bsort  <<<NBUCK, 256, 0, stream>>>(part, bbase, csr, rowptr, deg, dis);

    // layer 1
    k_mm64  <<<(N + 255) / 256, 256, 0, stream>>>(x, W1, dis, bufA, N);
    k_gather<<<(N + 3) / 4, 256, 0, stream>>>(bufA, csr, rowptr, deg, dis, b1, bufB, N);
    // layer 2
    k_mm64  <<<(N + 255) / 256, 256, 0, stream>>>(bufB, W2, dis, bufA, N);
    k_gather<<<(N + 3) / 4, 256, 0, stream>>>(bufA, csr, rowptr, deg, dis, b2, bufB, N);
    // head
    k_out   <<<(N + 255) / 256, 256, 0, stream>>>(bufB, Wp, bp, out, N);
}